// Round 3
// baseline (1878.484 us; speedup 1.0000x reference)
//
#include <hip/hip_runtime.h>

#define N_NODES 20000
#define N_EDGES 320000
#define HDIM    128
#define PI_F    3.14159265358979323846f
#define CUTOFF_R 5.0f

__device__ __forceinline__ float silu_f(float x) { return x / (1.0f + __expf(-x)); }
__device__ __forceinline__ float cutoff_f(float d) {
    return (d < CUTOFF_R) ? 0.5f * (__cosf(PI_F * d * (1.0f / CUTOFF_R)) + 1.0f) : 0.0f;
}

// ---------------------------------------------------------------------------
// LayerNorm: one wave per row
// ---------------------------------------------------------------------------
__global__ __launch_bounds__(256) void ln_kernel(
    const float* __restrict__ x, const float* __restrict__ gamma,
    const float* __restrict__ beta, float* __restrict__ out)
{
    int row  = blockIdx.x * 4 + (threadIdx.x >> 6);
    int lane = threadIdx.x & 63;
    if (row >= N_NODES) return;
    const float* xr = x + (size_t)row * HDIM;
    float x0 = xr[lane], x1 = xr[lane + 64];
    float s  = x0 + x1;
    float s2 = x0 * x0 + x1 * x1;
#pragma unroll
    for (int m = 32; m >= 1; m >>= 1) {
        s  += __shfl_xor(s,  m, 64);
        s2 += __shfl_xor(s2, m, 64);
    }
    float mean = s * (1.0f / 128.0f);
    float var  = s2 * (1.0f / 128.0f) - mean * mean;
    float rstd = rsqrtf(var + 1e-5f);
    out[row * HDIM + lane]      = (x0 - mean) * rstd * gamma[lane]      + beta[lane];
    out[row * HDIM + lane + 64] = (x1 - mean) * rstd * gamma[lane + 64] + beta[lane + 64];
}

// ---------------------------------------------------------------------------
// Counting sort of edges by destination i
// ---------------------------------------------------------------------------
__global__ __launch_bounds__(256) void count_kernel(const int* __restrict__ ei, int* __restrict__ cnt) {
    int e = blockIdx.x * 256 + threadIdx.x;
    if (e < N_EDGES) atomicAdd(&cnt[ei[e]], 1);
}

__global__ __launch_bounds__(1024) void scan_kernel(const int* __restrict__ cnt, int* __restrict__ ofs) {
    __shared__ int part[1024];
    int tid = threadIdx.x;
    const int PER = 20;              // 1024*20 >= 20000
    int base = tid * PER;
    int s = 0;
    for (int t = 0; t < PER; ++t) { int b = base + t; if (b < N_NODES) s += cnt[b]; }
    part[tid] = s;
    __syncthreads();
    for (int off = 1; off < 1024; off <<= 1) {
        int v = (tid >= off) ? part[tid - off] : 0;
        __syncthreads();
        part[tid] += v;
        __syncthreads();
    }
    int run = (tid > 0) ? part[tid - 1] : 0;
    for (int t = 0; t < PER; ++t) {
        int b = base + t;
        if (b < N_NODES) { ofs[b] = run; run += cnt[b]; }
    }
}

__global__ __launch_bounds__(256) void scatter_kernel(const int* __restrict__ ei,
                                                      int* __restrict__ ofs, int* __restrict__ perm) {
    int e = blockIdx.x * 256 + threadIdx.x;
    if (e < N_EDGES) { int p = atomicAdd(&ofs[ei[e]], 1); perm[p] = e; }
}

// ---------------------------------------------------------------------------
// Generic fp32 GEMM v2: OUT[M x C] = A[M x 128] @ W[128 x C] (+bias)
// 128x128 tile, 256 threads, 8x8 per thread, transposed-A LDS.
// ---------------------------------------------------------------------------
template <bool BIAS>
__global__ __launch_bounds__(256) void gemm128_v2(
    const float* __restrict__ A, const float* __restrict__ W,
    const float* __restrict__ bias, float* __restrict__ out, int M, int C)
{
    __shared__ float At[32][132];   // [k][row], stride 132 (bank-safe, 16B aligned rows)
    __shared__ float Ws[32][128];   // [k][col]
    int tid = threadIdx.x, tx = tid & 15, ty = tid >> 4;
    int m0 = blockIdx.x * 128, n0 = blockIdx.y * 128;
    float acc[8][8];
#pragma unroll
    for (int r = 0; r < 8; ++r)
#pragma unroll
        for (int c = 0; c < 8; ++c) acc[r][c] = 0.f;

    for (int k0 = 0; k0 < 128; k0 += 32) {
        __syncthreads();
#pragma unroll
        for (int p = 0; p < 4; ++p) {
            int f = tid + p * 256, ar = f >> 3, k4 = (f & 7) * 4, gr = m0 + ar;
            float4 v = (gr < M) ? *(const float4*)&A[(size_t)gr * 128 + k0 + k4]
                                : make_float4(0.f, 0.f, 0.f, 0.f);
            At[k4 + 0][ar] = v.x; At[k4 + 1][ar] = v.y;
            At[k4 + 2][ar] = v.z; At[k4 + 3][ar] = v.w;
        }
#pragma unroll
        for (int p = 0; p < 4; ++p) {
            int f = tid + p * 256, kr = f >> 5, c4 = (f & 31) * 4;
            *(float4*)&Ws[kr][c4] = *(const float4*)&W[(size_t)(k0 + kr) * C + n0 + c4];
        }
        __syncthreads();
#pragma unroll
        for (int k = 0; k < 32; ++k) {
            float4 a0 = *(const float4*)&At[k][ty * 8], a1 = *(const float4*)&At[k][ty * 8 + 4];
            float4 w0 = *(const float4*)&Ws[k][tx * 8], w1 = *(const float4*)&Ws[k][tx * 8 + 4];
            float av[8] = {a0.x, a0.y, a0.z, a0.w, a1.x, a1.y, a1.z, a1.w};
            float wv[8] = {w0.x, w0.y, w0.z, w0.w, w1.x, w1.y, w1.z, w1.w};
#pragma unroll
            for (int r = 0; r < 8; ++r)
#pragma unroll
                for (int c = 0; c < 8; ++c) acc[r][c] += av[r] * wv[c];
        }
    }
    float bv[8];
    if (BIAS) {
        float4 b0 = *(const float4*)&bias[n0 + tx * 8], b1 = *(const float4*)&bias[n0 + tx * 8 + 4];
        bv[0] = b0.x; bv[1] = b0.y; bv[2] = b0.z; bv[3] = b0.w;
        bv[4] = b1.x; bv[5] = b1.y; bv[6] = b1.z; bv[7] = b1.w;
    }
#pragma unroll
    for (int r = 0; r < 8; ++r) {
        int gr = m0 + ty * 8 + r;
        if (gr < M) {
            float res[8];
#pragma unroll
            for (int c = 0; c < 8; ++c) { float v = acc[r][c]; if (BIAS) v += bv[c]; res[c] = v; }
            *(float4*)&out[(size_t)gr * C + n0 + tx * 8]     = make_float4(res[0], res[1], res[2], res[3]);
            *(float4*)&out[(size_t)gr * C + n0 + tx * 8 + 4] = make_float4(res[4], res[5], res[6], res[7]);
        }
    }
}

// ---------------------------------------------------------------------------
// K1: W_edge GEMM (rows via perm) + fused attn/msg epilogue + dedup sagg atomics.
// Writes msg in SORTED edge order. 128 edges x 128 cols per block.
// ---------------------------------------------------------------------------
__global__ __launch_bounds__(256) void k1_edge_gemm_msg(
    const float* __restrict__ edge_feats, const float* __restrict__ We,
    const float* __restrict__ be, const float* __restrict__ ns,
    const int* __restrict__ eidx, const float* __restrict__ dist,
    const float* __restrict__ alpha, const int* __restrict__ perm,
    float* __restrict__ msg, float* __restrict__ sagg)
{
    __shared__ float At[32][132];
    __shared__ float Ws[32][128];
    __shared__ int perm_s[128], i_s[128], j_s[128];
    __shared__ float d_s[128];
    int tid = threadIdx.x, tx = tid & 15, ty = tid >> 4;
    int e0 = blockIdx.x * 128;

    if (tid < 128) perm_s[tid] = perm[e0 + tid];
    __syncthreads();
    if (tid < 128) {
        int pe = perm_s[tid];
        i_s[tid] = eidx[pe]; j_s[tid] = eidx[N_EDGES + pe]; d_s[tid] = dist[pe];
    }

    float acc[8][8];
#pragma unroll
    for (int r = 0; r < 8; ++r)
#pragma unroll
        for (int c = 0; c < 8; ++c) acc[r][c] = 0.f;

    for (int k0 = 0; k0 < 128; k0 += 32) {
        __syncthreads();
#pragma unroll
        for (int p = 0; p < 4; ++p) {
            int f = tid + p * 256, ar = f >> 3, k4 = (f & 7) * 4;
            int gr = perm_s[ar];
            float4 v = *(const float4*)&edge_feats[(size_t)gr * 128 + k0 + k4];
            At[k4 + 0][ar] = v.x; At[k4 + 1][ar] = v.y;
            At[k4 + 2][ar] = v.z; At[k4 + 3][ar] = v.w;
        }
#pragma unroll
        for (int p = 0; p < 4; ++p) {
            int f = tid + p * 256, kr = f >> 5, c4 = (f & 31) * 4;
            *(float4*)&Ws[kr][c4] = *(const float4*)&We[(size_t)(k0 + kr) * 128 + c4];
        }
        __syncthreads();
#pragma unroll
        for (int k = 0; k < 32; ++k) {
            float4 a0 = *(const float4*)&At[k][ty * 8], a1 = *(const float4*)&At[k][ty * 8 + 4];
            float4 w0 = *(const float4*)&Ws[k][tx * 8], w1 = *(const float4*)&Ws[k][tx * 8 + 4];
            float av[8] = {a0.x, a0.y, a0.z, a0.w, a1.x, a1.y, a1.z, a1.w};
            float wv[8] = {w0.x, w0.y, w0.z, w0.w, w1.x, w1.y, w1.z, w1.w};
#pragma unroll
            for (int r = 0; r < 8; ++r)
#pragma unroll
                for (int c = 0; c < 8; ++c) acc[r][c] += av[r] * wv[c];
        }
    }

    // epilogue
    float bev[8], al[8];
    {
        float4 b0 = *(const float4*)&be[tx * 8], b1 = *(const float4*)&be[tx * 8 + 4];
        bev[0]=b0.x; bev[1]=b0.y; bev[2]=b0.z; bev[3]=b0.w; bev[4]=b1.x; bev[5]=b1.y; bev[6]=b1.z; bev[7]=b1.w;
        float4 a0 = *(const float4*)&alpha[tx * 8], a1 = *(const float4*)&alpha[tx * 8 + 4];
        al[0]=a0.x; al[1]=a0.y; al[2]=a0.z; al[3]=a0.w; al[4]=a1.x; al[5]=a1.y; al[6]=a1.z; al[7]=a1.w;
    }
    int cur = i_s[ty * 8];
    float sac[8];
#pragma unroll
    for (int c = 0; c < 8; ++c) sac[c] = 0.f;

    auto flush = [&](void) {
#pragma unroll
        for (int c = 0; c < 8; ++c) atomicAdd(&sagg[(size_t)cur * 128 + tx * 8 + c], sac[c]);
#pragma unroll
        for (int c = 0; c < 8; ++c) sac[c] = 0.f;
    };

#pragma unroll
    for (int r = 0; r < 8; ++r) {
        int row = ty * 8 + r;
        int gi = i_s[row], gj = j_s[row];
        float efv[8];
#pragma unroll
        for (int c = 0; c < 8; ++c) efv[c] = silu_f(acc[r][c] + bev[c]);
        const float* nip = &ns[(size_t)gi * 128 + tx * 8];
        const float* njp = &ns[(size_t)gj * 128 + tx * 8];
        float4 ni0 = *(const float4*)nip, ni1 = *(const float4*)(nip + 4);
        float4 nj0 = *(const float4*)njp, nj1 = *(const float4*)(njp + 4);
        float niv[8] = {ni0.x, ni0.y, ni0.z, ni0.w, ni1.x, ni1.y, ni1.z, ni1.w};
        float njv[8] = {nj0.x, nj0.y, nj0.z, nj0.w, nj1.x, nj1.y, nj1.z, nj1.w};
        float ps = 0.f;
#pragma unroll
        for (int c = 0; c < 8; ++c) ps += silu_f(niv[c] + njv[c] + efv[c]) * al[c];
        float hs = ps + __shfl_xor(ps, 1, 64);   // 16-wide head sum (tx pair)
        float attn = hs * cutoff_f(d_s[row]);
        float mv[8];
#pragma unroll
        for (int c = 0; c < 8; ++c) mv[c] = njv[c] * efv[c] * attn;
        *(float4*)&msg[(size_t)(e0 + row) * 128 + tx * 8]     = make_float4(mv[0], mv[1], mv[2], mv[3]);
        *(float4*)&msg[(size_t)(e0 + row) * 128 + tx * 8 + 4] = make_float4(mv[4], mv[5], mv[6], mv[7]);
        if (gi != cur) { flush(); cur = gi; }
#pragma unroll
        for (int c = 0; c < 8; ++c) sac[c] += mv[c];
    }
    flush();
}

// ---------------------------------------------------------------------------
// K2: W_p1 GEMM on sorted msg (64 x 256 tile) + vmsg epilogue + dedup vagg atomics
// ---------------------------------------------------------------------------
__global__ __launch_bounds__(256) void k2_p1_vmsg(
    const float* __restrict__ msg, const float* __restrict__ Wp1,
    const float* __restrict__ bp1, const float* __restrict__ node_vector,
    const int* __restrict__ eidx, const float* __restrict__ edge_vector,
    const int* __restrict__ perm, float* __restrict__ vagg)
{
    __shared__ float At[32][68];
    __shared__ float Ws[32][256];
    __shared__ int perm_s[64], i_s[64], j_s[64];
    __shared__ float ev_s[64][3];
    int tid = threadIdx.x, tx = tid & 31, ty = tid >> 5;
    int e0 = blockIdx.x * 64;

    if (tid < 64) perm_s[tid] = perm[e0 + tid];
    __syncthreads();
    if (tid < 64) {
        int pe = perm_s[tid];
        i_s[tid] = eidx[pe]; j_s[tid] = eidx[N_EDGES + pe];
    } else {
        int t = tid - 64;
        if (t < 192) { int el = t / 3, cm = t - el * 3; ev_s[el][cm] = edge_vector[(size_t)perm_s[el] * 3 + cm]; }
    }

    float acc[8][8];
#pragma unroll
    for (int r = 0; r < 8; ++r)
#pragma unroll
        for (int c = 0; c < 8; ++c) acc[r][c] = 0.f;

    for (int k0 = 0; k0 < 128; k0 += 32) {
        __syncthreads();
#pragma unroll
        for (int p = 0; p < 2; ++p) {
            int f = tid + p * 256, ar = f >> 3, k4 = (f & 7) * 4;
            float4 v = *(const float4*)&msg[(size_t)(e0 + ar) * 128 + k0 + k4];
            At[k4 + 0][ar] = v.x; At[k4 + 1][ar] = v.y;
            At[k4 + 2][ar] = v.z; At[k4 + 3][ar] = v.w;
        }
#pragma unroll
        for (int p = 0; p < 8; ++p) {
            int f = tid + p * 256, kr = f >> 6, c4 = (f & 63) * 4;
            *(float4*)&Ws[kr][c4] = *(const float4*)&Wp1[(size_t)(k0 + kr) * 256 + c4];
        }
        __syncthreads();
#pragma unroll
        for (int k = 0; k < 32; ++k) {
            float4 a0 = *(const float4*)&At[k][ty * 8], a1 = *(const float4*)&At[k][ty * 8 + 4];
            float4 w0 = *(const float4*)&Ws[k][tx * 8], w1 = *(const float4*)&Ws[k][tx * 8 + 4];
            float av[8] = {a0.x, a0.y, a0.z, a0.w, a1.x, a1.y, a1.z, a1.w};
            float wv[8] = {w0.x, w0.y, w0.z, w0.w, w1.x, w1.y, w1.z, w1.w};
#pragma unroll
            for (int r = 0; r < 8; ++r)
#pragma unroll
                for (int c = 0; c < 8; ++c) acc[r][c] += av[r] * wv[c];
        }
    }

    float bv[8];
    {
        float4 b0 = *(const float4*)&bp1[tx * 8], b1 = *(const float4*)&bp1[tx * 8 + 4];
        bv[0]=b0.x; bv[1]=b0.y; bv[2]=b0.z; bv[3]=b0.w; bv[4]=b1.x; bv[5]=b1.y; bv[6]=b1.z; bv[7]=b1.w;
    }
    bool lo = (tx < 16);
    int h0 = (tx & 15) * 8;
    int cur = i_s[ty * 8];
    float va0[8], va1[8];
#pragma unroll
    for (int c = 0; c < 8; ++c) { va0[c] = 0.f; va1[c] = 0.f; }

    auto flushv = [&](void) {
        if (lo) {
#pragma unroll
            for (int c = 0; c < 8; ++c) atomicAdd(&vagg[((size_t)cur * 3 + 0) * 128 + h0 + c], va0[c]);
#pragma unroll
            for (int c = 0; c < 8; ++c) atomicAdd(&vagg[((size_t)cur * 3 + 1) * 128 + h0 + c], va1[c]);
        } else {
#pragma unroll
            for (int c = 0; c < 8; ++c) atomicAdd(&vagg[((size_t)cur * 3 + 2) * 128 + h0 + c], va0[c]);
        }
#pragma unroll
        for (int c = 0; c < 8; ++c) { va0[c] = 0.f; va1[c] = 0.f; }
    };

#pragma unroll
    for (int r = 0; r < 8; ++r) {
        int row = ty * 8 + r;
        int gi = i_s[row], gj = j_s[row];
        float sv[8], ov[8];
#pragma unroll
        for (int c = 0; c < 8; ++c) sv[c] = silu_f(acc[r][c] + bv[c]);
#pragma unroll
        for (int c = 0; c < 8; ++c) ov[c] = __shfl_xor(sv[c], 16, 64);
        float s1[8], s2[8];
#pragma unroll
        for (int c = 0; c < 8; ++c) { s1[c] = lo ? sv[c] : ov[c]; s2[c] = lo ? ov[c] : sv[c]; }
        if (gi != cur) { flushv(); cur = gi; }
        const float* nvb = &node_vector[(size_t)gj * 3 * 128 + h0];
        if (lo) {
            float ev0 = ev_s[row][0], ev1 = ev_s[row][1];
            float4 a0 = *(const float4*)&nvb[0],       a1 = *(const float4*)&nvb[4];
            float4 b0 = *(const float4*)&nvb[128],     b1 = *(const float4*)&nvb[132];
            float na[8] = {a0.x, a0.y, a0.z, a0.w, a1.x, a1.y, a1.z, a1.w};
            float nb[8] = {b0.x, b0.y, b0.z, b0.w, b1.x, b1.y, b1.z, b1.w};
#pragma unroll
            for (int c = 0; c < 8; ++c) { va0[c] += na[c] * s1[c] + s2[c] * ev0; va1[c] += nb[c] * s1[c] + s2[c] * ev1; }
        } else {
            float ev2 = ev_s[row][2];
            float4 a0 = *(const float4*)&nvb[256],     a1 = *(const float4*)&nvb[260];
            float na[8] = {a0.x, a0.y, a0.z, a0.w, a1.x, a1.y, a1.z, a1.w};
#pragma unroll
            for (int c = 0; c < 8; ++c) va0[c] += na[c] * s1[c] + s2[c] * ev2;
        }
    }
    flushv();
}

// ---------------------------------------------------------------------------
// K3: W_f GEMM (original order) + cross-product sum_phi + residual
// ---------------------------------------------------------------------------
__global__ __launch_bounds__(256) void k3_wf_edgeout(
    const float* __restrict__ edge_feats, const float* __restrict__ Wf,
    const float* __restrict__ bf, const float* __restrict__ nvg,
    const int* __restrict__ eidx, const float* __restrict__ edge_vector,
    float* __restrict__ edge_out)
{
    __shared__ float At[32][132];
    __shared__ float Ws[32][128];
    __shared__ int i_s[128], j_s[128];
    __shared__ float evf[384];
    int tid = threadIdx.x, tx = tid & 15, ty = tid >> 4;
    int e0 = blockIdx.x * 128;

    if (tid < 128) { i_s[tid] = eidx[e0 + tid]; j_s[tid] = eidx[N_EDGES + e0 + tid]; }
    evf[tid < 256 ? tid : 0] = edge_vector[(size_t)e0 * 3 + (tid < 256 ? tid : 0)];
    if (tid < 128) evf[256 + tid] = edge_vector[(size_t)e0 * 3 + 256 + tid];

    float acc[8][8];
#pragma unroll
    for (int r = 0; r < 8; ++r)
#pragma unroll
        for (int c = 0; c < 8; ++c) acc[r][c] = 0.f;

    for (int k0 = 0; k0 < 128; k0 += 32) {
        __syncthreads();
#pragma unroll
        for (int p = 0; p < 4; ++p) {
            int f = tid + p * 256, ar = f >> 3, k4 = (f & 7) * 4;
            float4 v = *(const float4*)&edge_feats[(size_t)(e0 + ar) * 128 + k0 + k4];
            At[k4 + 0][ar] = v.x; At[k4 + 1][ar] = v.y;
            At[k4 + 2][ar] = v.z; At[k4 + 3][ar] = v.w;
        }
#pragma unroll
        for (int p = 0; p < 4; ++p) {
            int f = tid + p * 256, kr = f >> 5, c4 = (f & 31) * 4;
            *(float4*)&Ws[kr][c4] = *(const float4*)&Wf[(size_t)(k0 + kr) * 128 + c4];
        }
        __syncthreads();
#pragma unroll
        for (int k = 0; k < 32; ++k) {
            float4 a0 = *(const float4*)&At[k][ty * 8], a1 = *(const float4*)&At[k][ty * 8 + 4];
            float4 w0 = *(const float4*)&Ws[k][tx * 8], w1 = *(const float4*)&Ws[k][tx * 8 + 4];
            float av[8] = {a0.x, a0.y, a0.z, a0.w, a1.x, a1.y, a1.z, a1.w};
            float wv[8] = {w0.x, w0.y, w0.z, w0.w, w1.x, w1.y, w1.z, w1.w};
#pragma unroll
            for (int r = 0; r < 8; ++r)
#pragma unroll
                for (int c = 0; c < 8; ++c) acc[r][c] += av[r] * wv[c];
        }
    }

    float bfv[8];
    {
        float4 b0 = *(const float4*)&bf[tx * 8], b1 = *(const float4*)&bf[tx * 8 + 4];
        bfv[0]=b0.x; bfv[1]=b0.y; bfv[2]=b0.z; bfv[3]=b0.w; bfv[4]=b1.x; bfv[5]=b1.y; bfv[6]=b1.z; bfv[7]=b1.w;
    }
#pragma unroll
    for (int r = 0; r < 8; ++r) {
        int row = ty * 8 + r;
        int e = e0 + row;
        int gi = i_s[row], gj = j_s[row];
        float ev0 = evf[row * 3 + 0], ev1 = evf[row * 3 + 1], ev2 = evf[row * 3 + 2];
        float nvi[3][8], nvj[3][8];
#pragma unroll
        for (int d = 0; d < 3; ++d) {
            const float* pi = &nvg[((size_t)gi * 3 + d) * 128 + tx * 8];
            const float* pj = &nvg[((size_t)gj * 3 + d) * 128 + tx * 8];
            float4 a0 = *(const float4*)pi, a1 = *(const float4*)(pi + 4);
            float4 b0 = *(const float4*)pj, b1 = *(const float4*)(pj + 4);
            nvi[d][0]=a0.x; nvi[d][1]=a0.y; nvi[d][2]=a0.z; nvi[d][3]=a0.w;
            nvi[d][4]=a1.x; nvi[d][5]=a1.y; nvi[d][6]=a1.z; nvi[d][7]=a1.w;
            nvj[d][0]=b0.x; nvj[d][1]=b0.y; nvj[d][2]=b0.z; nvj[d][3]=b0.w;
            nvj[d][4]=b1.x; nvj[d][5]=b1.y; nvj[d][6]=b1.z; nvj[d][7]=b1.w;
        }
        float4 f0 = *(const float4*)&edge_feats[(size_t)e * 128 + tx * 8];
        float4 f1 = *(const float4*)&edge_feats[(size_t)e * 128 + tx * 8 + 4];
        float efr[8] = {f0.x, f0.y, f0.z, f0.w, f1.x, f1.y, f1.z, f1.w};
        float res[8];
#pragma unroll
        for (int c = 0; c < 8; ++c) {
            float ci0 = nvi[1][c] * ev2 - nvi[2][c] * ev1;
            float ci1 = nvi[2][c] * ev0 - nvi[0][c] * ev2;
            float ci2 = nvi[0][c] * ev1 - nvi[1][c] * ev0;
            float cj0 = nvj[1][c] * ev2 - nvj[2][c] * ev1;
            float cj1 = nvj[2][c] * ev0 - nvj[0][c] * ev2;
            float cj2 = nvj[0][c] * ev1 - nvj[1][c] * ev0;
            float sp  = ci0 * cj0 + ci1 * cj1 + ci2 * cj2;
            res[c] = efr[c] + silu_f(acc[r][c] + bfv[c]) * sp;
        }
        *(float4*)&edge_out[(size_t)e * 128 + tx * 8]     = make_float4(res[0], res[1], res[2], res[3]);
        *(float4*)&edge_out[(size_t)e * 128 + tx * 8 + 4] = make_float4(res[4], res[5], res[6], res[7]);
    }
}

// ---------------------------------------------------------------------------
__global__ __launch_bounds__(256) void node_add_kernel(
    const float* __restrict__ ns0, const float* __restrict__ sagg,
    const float* __restrict__ nv0, const float* __restrict__ vagg,
    float* __restrict__ ns_new, float* __restrict__ nv_new)
{
    int idx = blockIdx.x * 256 + threadIdx.x;
    const int nsf4 = N_NODES * HDIM / 4;
    if (idx < nsf4) {
        float4 a = ((const float4*)ns0)[idx];
        float4 b = ((const float4*)sagg)[idx];
        ((float4*)ns_new)[idx] = make_float4(a.x + b.x, a.y + b.y, a.z + b.z, a.w + b.w);
    } else {
        int k = idx - nsf4;
        float4 a = ((const float4*)nv0)[k];
        float4 b = ((const float4*)vagg)[k];
        ((float4*)nv_new)[k] = make_float4(a.x + b.x, a.y + b.y, a.z + b.z, a.w + b.w);
    }
}

__global__ __launch_bounds__(256) void final_node_kernel(
    const float* __restrict__ v12, const float* __restrict__ p123,
    const float* __restrict__ ns_new, const float* __restrict__ nv_new,
    float* __restrict__ out_s, float* __restrict__ out_v)
{
    int idx = blockIdx.x * 256 + threadIdx.x;
    int n = idx >> 7, h = idx & 127;
    float tri = 0.f, q2 = 0.f;
    float v1d[3];
#pragma unroll
    for (int d = 0; d < 3; ++d) {
        float v1 = v12[((size_t)n * 3 + d) * 256 + h];
        float v2 = v12[((size_t)n * 3 + d) * 256 + 128 + h];
        v1d[d] = v1;
        tri += v1 * v2;
        q2  += v2 * v2;
    }
    float nrm = sqrtf(q2 + 1e-8f);
    float qua = nrm * nrm * nrm;
    float p1 = p123[(size_t)n * 384 + h];
    float p2 = p123[(size_t)n * 384 + 128 + h];
    float p3 = p123[(size_t)n * 384 + 256 + h];
    out_s[idx] = ns_new[idx] + (qua + tri) * p1 + p2;
#pragma unroll
    for (int d = 0; d < 3; ++d)
        out_v[((size_t)n * 3 + d) * 128 + h] = nv_new[((size_t)n * 3 + d) * 128 + h] + v1d[d] * p3;
}

// ---------------------------------------------------------------------------
extern "C" void kernel_launch(void* const* d_in, const int* in_sizes, int n_in,
                              void* d_out, int out_size, void* d_ws, size_t ws_size,
                              hipStream_t stream)
{
    const float* node_scalar = (const float*)d_in[0];
    const float* node_vector = (const float*)d_in[1];
    const int*   edge_index  = (const int*)d_in[2];
    const float* dist        = (const float*)d_in[3];
    const float* edge_feats  = (const float*)d_in[4];
    const float* edge_vector = (const float*)d_in[5];
    const float* ln_gamma    = (const float*)d_in[6];
    const float* ln_beta     = (const float*)d_in[7];
    const float* alpha       = (const float*)d_in[8];
    const float* W_cross     = (const float*)d_in[9];
    const float* W_node      = (const float*)d_in[10];
    const float* b_node      = (const float*)d_in[11];
    const float* W_edge      = (const float*)d_in[12];
    const float* b_edge      = (const float*)d_in[13];
    const float* W_p1        = (const float*)d_in[14];
    const float* b_p1        = (const float*)d_in[15];
    const float* W_p2        = (const float*)d_in[16];
    const float* b_p2        = (const float*)d_in[17];
    const float* W_vec       = (const float*)d_in[18];
    const float* W_f         = (const float*)d_in[19];
    const float* b_f         = (const float*)d_in[20];

    float* out_scalar = (float*)d_out;
    float* out_vector = out_scalar + N_NODES * HDIM;       // 2,560,000
    float* out_edge   = out_vector + N_NODES * 3 * HDIM;   // +7,680,000
    float* msg        = out_edge;                          // scratch: later overwritten by K3

    float* ws   = (float*)d_ws;
    float* sc   = ws;               // scalar_out / ns_new (2.56M)
    float* ns   = ws + 2560000;     // (2.56M)
    float* nv   = ws + 5120000;     // W_cross out / nv_new (7.68M)
    float* sagg = ws + 12800000;    // (2.56M)
    float* vagg = ws + 15360000;    // (7.68M)
    float* v12  = ws + 23040000;    // (15.36M)
    float* p123 = ws + 38400000;    // (7.68M)
    int*   perm = (int*)(ws + 46080000);  // 320,000 ints
    int*   cnt  = (int*)(ws + 46400000);  // 20,000
    int*   ofs  = (int*)(ws + 46420000);  // 20,000

    hipMemsetAsync(sagg, 0, (size_t)(2560000 + 7680000) * sizeof(float), stream);
    hipMemsetAsync(cnt, 0, (size_t)N_NODES * sizeof(int), stream);

    // sort edges by destination i
    hipLaunchKernelGGL(count_kernel,   dim3(1250), dim3(256),  0, stream, edge_index, cnt);
    hipLaunchKernelGGL(scan_kernel,    dim3(1),    dim3(1024), 0, stream, cnt, ofs);
    hipLaunchKernelGGL(scatter_kernel, dim3(1250), dim3(256),  0, stream, edge_index, ofs, perm);

    // node-level precompute
    hipLaunchKernelGGL(ln_kernel, dim3(5000), dim3(256), 0, stream,
                       node_scalar, ln_gamma, ln_beta, sc);
    hipLaunchKernelGGL((gemm128_v2<true>),  dim3(157, 1), dim3(256), 0, stream,
                       sc, W_node, b_node, ns, N_NODES, 128);
    hipLaunchKernelGGL((gemm128_v2<false>), dim3(469, 1), dim3(256), 0, stream,
                       node_vector, W_cross, nullptr, nv, 3 * N_NODES, 128);

    // edge pipeline (sorted)
    hipLaunchKernelGGL(k1_edge_gemm_msg, dim3(2500), dim3(256), 0, stream,
                       edge_feats, W_edge, b_edge, ns, edge_index, dist, alpha, perm, msg, sagg);
    hipLaunchKernelGGL(k2_p1_vmsg, dim3(5000), dim3(256), 0, stream,
                       msg, W_p1, b_p1, node_vector, edge_index, edge_vector, perm, vagg);
    hipLaunchKernelGGL(k3_wf_edgeout, dim3(2500), dim3(256), 0, stream,
                       edge_feats, W_f, b_f, nv, edge_index, edge_vector, out_edge);

    // node update
    hipLaunchKernelGGL(node_add_kernel, dim3(10000), dim3(256), 0, stream,
                       node_scalar, sagg, node_vector, vagg, sc, nv);
    hipLaunchKernelGGL((gemm128_v2<false>), dim3(469, 2), dim3(256), 0, stream,
                       nv, W_vec, nullptr, v12, 3 * N_NODES, 256);
    hipLaunchKernelGGL((gemm128_v2<true>),  dim3(157, 3), dim3(256), 0, stream,
                       sc, W_p2, b_p2, p123, N_NODES, 384);
    hipLaunchKernelGGL(final_node_kernel, dim3(10000), dim3(256), 0, stream,
                       v12, p123, sc, nv, out_scalar, out_vector);
}